// Round 4
// baseline (77.292 us; speedup 1.0000x reference)
//
#include <hip/hip_runtime.h>

// Log-signature depth 3, d=8, L=256, B=2048 — single fused kernel.
// One block (4 waves) per batch element; wave w scans time chunk [64w, 64w+64)
// (dx row t=255 zeroed = Chen identity step), chunks folded by wave 0:
//   C1=A1+B1; C2=A2+B2+A1⊗B1; C3=A3+B3+A1⊗B2+A2⊗B1.
// Lane l=(i=l>>3, j=l&7): s1=S1[i] (kept as h1=0.5*S1[i]), s2=S2[i][j],
// s3[k]=S3[i][j][k]. Step (old state on RHS):
//   S3[k] += (S2 + (0.5*S1[i] + dx[i]/6)*dx[j]) * dx[k]
//   S2    += (S1[i] + 0.5*dx[i]) * dx[j];   S1[i] += dx[i]
// KEY: the broadcast row dx[t][0..7] for the k-loop is NOT read through the
// LDS pipe per step (that was 24 cyc/step/wave of CU-shared LDS bandwidth).
// Instead, lane 8u+c stages dx[t0+u][c] with ONE b32 read per 8 steps, and
// per step the 8 row values are pulled to SGPRs with v_readlane (VALU pipe),
// so each k-FMA is v_fma v,v,s,v. dxi/dxj come from a transposed padded LDS
// image (stride 260 → banks 4i..4i+3, broadcast within 8-lane groups, free).

#define LEN 256
#define DCH 8
#define NW 4
#define CHUNK 64
#define TPAD 260
#define OUTSTRIDE (DCH + DCH*DCH + DCH*DCH*DCH)  // 584

__global__ __launch_bounds__(256) void logsig_fused(const float* __restrict__ x,
                                                    float* __restrict__ out) {
    __shared__ __align__(16) float dxT[DCH][TPAD];   // transposed dx, 8320 B
    __shared__ __align__(16) float sig1[NW][8];
    __shared__ __align__(16) float sig2[NW][64];
    __shared__ __align__(16) float sig3[NW][512];
    __shared__ __align__(16) float s1buf[8];
    __shared__ __align__(16) float s2buf[64];

    const int tid  = threadIdx.x;
    const int w    = tid >> 6;
    const int lane = tid & 63;
    const int i    = lane >> 3;
    const int j    = lane & 7;
    const int b    = blockIdx.x;

    // ---- Stage dx transposed into LDS: dxT[c][t] = x[t+1][c]-x[t][c] ----
    const float4* x4 = (const float4*)(x + (size_t)b * (LEN * DCH));
    for (int f = tid; f < 512; f += 256) {   // f indexes float4s of dx
        float4 dv;
        if (f < 510) {
            float4 a = x4[f];
            float4 c = x4[f + 2];
            dv.x = c.x - a.x; dv.y = c.y - a.y; dv.z = c.z - a.z; dv.w = c.w - a.w;
        } else {
            dv.x = 0.f; dv.y = 0.f; dv.z = 0.f; dv.w = 0.f;  // zero row t=255
        }
        int t  = f >> 1;
        int c0 = (f & 1) * 4;
        dxT[c0 + 0][t] = dv.x;
        dxT[c0 + 1][t] = dv.y;
        dxT[c0 + 2][t] = dv.z;
        dxT[c0 + 3][t] = dv.w;
    }
    __syncthreads();

    // ---- Chunk scan: 64 steps per wave, 8-step macro blocks ----
    float h1 = 0.f, s2 = 0.f;     // h1 = 0.5*S1[i]
    float s3[8];
#pragma unroll
    for (int k = 0; k < 8; ++k) s3[k] = 0.f;

    const float c6 = 1.f / 6.f;
    const float* vip = &dxT[i][w * CHUNK];
    const float* vjp = &dxT[j][w * CHUNK];
    const float* rvp = &dxT[lane & 7][w * CHUNK + (lane >> 3)];  // lane 8u+c -> dx[t0+u][c]

#define STEP(DXI, DXJ, U)                                                     \
    do {                                                                      \
        float dxi = (DXI), dxj = (DXJ);                                       \
        float r0 = __int_as_float(__builtin_amdgcn_readlane(rv, 8*(U)+0));    \
        float r1 = __int_as_float(__builtin_amdgcn_readlane(rv, 8*(U)+1));    \
        float r2 = __int_as_float(__builtin_amdgcn_readlane(rv, 8*(U)+2));    \
        float r3 = __int_as_float(__builtin_amdgcn_readlane(rv, 8*(U)+3));    \
        float r4 = __int_as_float(__builtin_amdgcn_readlane(rv, 8*(U)+4));    \
        float r5 = __int_as_float(__builtin_amdgcn_readlane(rv, 8*(U)+5));    \
        float r6 = __int_as_float(__builtin_amdgcn_readlane(rv, 8*(U)+6));    \
        float r7 = __int_as_float(__builtin_amdgcn_readlane(rv, 8*(U)+7));    \
        float h1n = fmaf(0.5f, dxi, h1);   /* 0.5*(S1+dxi) */                 \
        float uu  = h1 + h1n;              /* S1 + 0.5*dxi  */                \
        float tt  = fmaf(c6, dxi, h1);     /* 0.5*S1 + dxi/6 */               \
        float w3  = fmaf(tt, dxj, s2);                                        \
        s3[0] = fmaf(w3, r0, s3[0]);                                          \
        s3[1] = fmaf(w3, r1, s3[1]);                                          \
        s3[2] = fmaf(w3, r2, s3[2]);                                          \
        s3[3] = fmaf(w3, r3, s3[3]);                                          \
        s3[4] = fmaf(w3, r4, s3[4]);                                          \
        s3[5] = fmaf(w3, r5, s3[5]);                                          \
        s3[6] = fmaf(w3, r6, s3[6]);                                          \
        s3[7] = fmaf(w3, r7, s3[7]);                                          \
        s2 = fmaf(uu, dxj, s2);                                               \
        h1 = h1n;                                                             \
    } while (0)

    for (int tb = 0; tb < CHUNK; tb += 8) {
        int rv = __float_as_int(rvp[tb]);                // ds_read_b32, 2-way (free)
        float4 vi0 = *(const float4*)(vip + tb);         // dxi, steps 0..3
        float4 vi1 = *(const float4*)(vip + tb + 4);     // dxi, steps 4..7
        float4 vj0 = *(const float4*)(vjp + tb);
        float4 vj1 = *(const float4*)(vjp + tb + 4);
        STEP(vi0.x, vj0.x, 0);
        STEP(vi0.y, vj0.y, 1);
        STEP(vi0.z, vj0.z, 2);
        STEP(vi0.w, vj0.w, 3);
        STEP(vi1.x, vj1.x, 4);
        STEP(vi1.y, vj1.y, 5);
        STEP(vi1.z, vj1.z, 6);
        STEP(vi1.w, vj1.w, 7);
    }
#undef STEP

    float s1 = h1 + h1;   // S1[i] (exact *2)

    // ---- Publish chunk signatures ----
    if (j == 0) sig1[w][i] = s1;
    sig2[w][lane] = s2;
    float* sp = &sig3[w][lane * 8];
    *(float4*)(sp)     = make_float4(s3[0], s3[1], s3[2], s3[3]);
    *(float4*)(sp + 4) = make_float4(s3[4], s3[5], s3[6], s3[7]);
    __syncthreads();

    if (w != 0) return;

    // ---- Fold chunks 1..3 into wave 0's registers (A=accum, B=chunk c) ----
    for (int c = 1; c < NW; ++c) {
        float B1i  = sig1[c][i];
        float B1j  = sig1[c][j];
        float B2ij = sig2[c][lane];
        float4 b1a = *(const float4*)&sig1[c][0];
        float4 b1b = *(const float4*)&sig1[c][4];
        const float* b2row = &sig2[c][j * 8];
        float4 b2a = *(const float4*)(b2row);
        float4 b2b = *(const float4*)(b2row + 4);
        const float* b3row = &sig3[c][lane * 8];
        float4 b3a = *(const float4*)(b3row);
        float4 b3b = *(const float4*)(b3row + 4);
        float B1k[8]  = {b1a.x, b1a.y, b1a.z, b1a.w, b1b.x, b1b.y, b1b.z, b1b.w};
        float B2jk[8] = {b2a.x, b2a.y, b2a.z, b2a.w, b2b.x, b2b.y, b2b.z, b2b.w};
        float B3[8]   = {b3a.x, b3a.y, b3a.z, b3a.w, b3b.x, b3b.y, b3b.z, b3b.w};
#pragma unroll
        for (int k = 0; k < 8; ++k)   // uses OLD s1 (A1), OLD s2 (A2)
            s3[k] = s3[k] + B3[k] + s1 * B2jk[k] + s2 * B1k[k];
        s2 = s2 + B2ij + s1 * B1j;    // uses OLD s1
        s1 = s1 + B1i;
    }

    // ---- Log map epilogue (wave-internal LDS exchange) ----
    if (j == 0) s1buf[i] = s1;
    s2buf[lane] = s2;

    float S1r[8], S2rj[8];
#pragma unroll
    for (int k = 0; k < 8; ++k) S1r[k] = s1buf[k];
#pragma unroll
    for (int k = 0; k < 8; ++k) S2rj[k] = s2buf[j * 8 + k];
    float s1j = s1buf[j];

    float* ob = out + (size_t)b * OUTSTRIDE;
    if (lane < 8) ob[lane] = s1buf[lane];            // l1
    ob[8 + lane] = fmaf(-0.5f * s1, s1j, s2);        // l2

    float c3 = (1.f / 3.f) * s1 * s1j;
    float l3[8];
#pragma unroll
    for (int k = 0; k < 8; ++k)
        l3[k] = s3[k] - 0.5f * (s1 * S2rj[k] + s2 * S1r[k]) + c3 * S1r[k];
    float* p3 = ob + 72 + lane * 8;
    *(float4*)(p3)     = make_float4(l3[0], l3[1], l3[2], l3[3]);
    *(float4*)(p3 + 4) = make_float4(l3[4], l3[5], l3[6], l3[7]);
}

extern "C" void kernel_launch(void* const* d_in, const int* in_sizes, int n_in,
                              void* d_out, int out_size, void* d_ws, size_t ws_size,
                              hipStream_t stream) {
    const float* x = (const float*)d_in[0];
    float* out = (float*)d_out;
    const int B = in_sizes[0] / (LEN * DCH);   // 2048
    hipLaunchKernelGGL(logsig_fused, dim3(B), dim3(256), 0, stream, x, out);
}